// Round 6
// baseline (135.317 us; speedup 1.0000x reference)
//
#include <hip/hip_runtime.h>

// Trilinear grid_sample (align_corners=False, zeros padding) of 256^3 fp32
// volume, scaled by 100.
//
// Round 8: pad the scatter's global bucket counters to one per 64B line.
//   Round-7 post-mortem: scatter+gather each < 41us but sum ~55us. Suspected
//   hidden cost: cursor[2048] u32 = 128 cachelines receiving 417K global
//   atomicAdds (~3300 serialized RMWs on the hottest line) -- invisible in
//   FETCH/WRITE, pacing every pipeline variant since round 3. Fix: stride
//   counters by 16 u32 (64B) so per-bucket atomics parallelize across 2048
//   lines. Everything else (scatter structure, persistent double-buffered
//   LDS gather, direct fallback) unchanged from the verified round-7 code.

#define RES 256
#define TZ 4              // z-slices per tile
#define TY 8              // y-rows per tile
#define NZT 64            // 256/TZ
#define NYT 32            // 256/TY
#define NBKT 2048         // NZT*NYT buckets
#define CAP 352           // slots/bucket (avg 256, +6 sigma; overflow->direct)
#define CSTRIDE 16        // u32 stride between counters (64B line each)
#define NROW 45           // (TZ+1)*(TY+1) staged rows per tile
#define TILEF (NROW * 256) // floats per LDS buffer (45 KB)
#define NTHREADS 256

typedef float vfloat4 __attribute__((ext_vector_type(4)));

// ---- direct-path interp (verified, absmax 3.8e-6) ----

__device__ __forceinline__ float interp_point(
    const float* __restrict__ vol, float rx, float ry, float rz)
{
    float ix = ((rx * 2.0f + 1.0f) * (float)RES - 1.0f) * 0.5f;
    float iy = ((ry * 2.0f + 1.0f) * (float)RES - 1.0f) * 0.5f;
    float iz = ((rz * 2.0f + 1.0f) * (float)RES - 1.0f) * 0.5f;

    float x0f = floorf(ix), y0f = floorf(iy), z0f = floorf(iz);
    float tx = ix - x0f, ty = iy - y0f, tz = iz - z0f;

    int x0 = (int)x0f, y0 = (int)y0f, z0 = (int)z0f;
    int x1 = x0 + 1, y1 = y0 + 1, z1 = z0 + 1;

    float wx0 = (x0 >= 0 && x0 < RES) ? (1.0f - tx) : 0.0f;
    float wx1 = (x1 >= 0 && x1 < RES) ? tx : 0.0f;
    float wy0 = (y0 >= 0 && y0 < RES) ? (1.0f - ty) : 0.0f;
    float wy1 = (y1 >= 0 && y1 < RES) ? ty : 0.0f;
    float wz0 = (z0 >= 0 && z0 < RES) ? (1.0f - tz) : 0.0f;
    float wz1 = (z1 >= 0 && z1 < RES) ? tz : 0.0f;

    int xc0 = min(max(x0, 0), RES - 1), xc1 = min(max(x1, 0), RES - 1);
    int yc0 = min(max(y0, 0), RES - 1), yc1 = min(max(y1, 0), RES - 1);
    int zc0 = min(max(z0, 0), RES - 1), zc1 = min(max(z1, 0), RES - 1);

    int r00 = (zc0 * RES + yc0) * RES;
    int r01 = (zc0 * RES + yc1) * RES;
    int r10 = (zc1 * RES + yc0) * RES;
    int r11 = (zc1 * RES + yc1) * RES;

    float v000 = vol[r00 + xc0];
    float v001 = vol[r00 + xc1];
    float v010 = vol[r01 + xc0];
    float v011 = vol[r01 + xc1];
    float v100 = vol[r10 + xc0];
    float v101 = vol[r10 + xc1];
    float v110 = vol[r11 + xc0];
    float v111 = vol[r11 + xc1];

    float c00 = v000 * wx0 + v001 * wx1;
    float c01 = v010 * wx0 + v011 * wx1;
    float c10 = v100 * wx0 + v101 * wx1;
    float c11 = v110 * wx0 + v111 * wx1;
    float c0 = c00 * wy0 + c01 * wy1;
    float c1 = c10 * wy0 + c11 * wy1;
    return 100.0f * (c0 * wz0 + c1 * wz1);
}

// ---- pass 1: bucket-scatter points by (z,y) tile ----
// block = 256 threads, 1024 points/block (4/thread). Global counters are
// line-padded: atomics to different buckets never share a cacheline.

__global__ __launch_bounds__(256) void VolumeExplicit_scatter_kernel(
    const float* __restrict__ x,
    const float* __restrict__ vol,
    float* __restrict__ out,
    vfloat4* __restrict__ sorted,
    unsigned* __restrict__ cursor)
{
    __shared__ unsigned lh[NBKT];
    __shared__ unsigned lbase[NBKT];
    int t = threadIdx.x;
    int base_i = blockIdx.x * 1024;

    for (int b = t; b < NBKT; b += 256) lh[b] = 0;
    __syncthreads();

    float px[4], py[4], pz[4];
    int bk[4];
    unsigned lr[4];
    #pragma unroll
    for (int k = 0; k < 4; ++k) {
        int i = base_i + (k << 8) + t;
        px[k] = __builtin_nontemporal_load(&x[3 * i + 0]);
        py[k] = __builtin_nontemporal_load(&x[3 * i + 1]);
        pz[k] = __builtin_nontemporal_load(&x[3 * i + 2]);
        float iy = ((py[k] * 2.0f + 1.0f) * (float)RES - 1.0f) * 0.5f;
        float iz = ((pz[k] * 2.0f + 1.0f) * (float)RES - 1.0f) * 0.5f;
        int y0 = (int)floorf(iy);
        int z0 = (int)floorf(iz);
        int yc0 = min(max(y0, 0), RES - 1);
        int zc0 = min(max(z0, 0), RES - 1);
        int b_ = (zc0 >> 2) * NYT + (yc0 >> 3);
        bk[k] = b_;
        lr[k] = atomicAdd(&lh[b_], 1u);
    }
    __syncthreads();

    for (int b = t; b < NBKT; b += 256) {
        unsigned c = lh[b];
        lbase[b] = c ? atomicAdd(&cursor[b * CSTRIDE], c) : 0u;  // padded line
    }
    __syncthreads();

    #pragma unroll
    for (int k = 0; k < 4; ++k) {
        int i = base_i + (k << 8) + t;
        unsigned pos = lbase[bk[k]] + lr[k];
        if (pos < CAP) {
            vfloat4 v;
            v.x = px[k]; v.y = py[k]; v.z = pz[k];
            v.w = __uint_as_float((unsigned)i);
            sorted[(size_t)bk[k] * CAP + pos] = v;
        } else {
            // overflow insurance: compute direct (correctness-safe)
            out[i] = interp_point(vol, px[k], py[k], pz[k]);
        }
    }
}

// ---- staging: one tile (45 rows x 1KB) via global_load_lds ----
// Each row = ONE wave-instruction: per-lane global src = row + lane*16B,
// wave-uniform LDS dst; lane data lands at dst + lane*16 (linear, matches).

__device__ __forceinline__ void stage_tile(
    const float* __restrict__ vol, float* dst, int zt, int yt, int lane, int w)
{
    for (int q = w; q < NROW; q += 4) {
        int zr = q / 9;
        int yr = q - zr * 9;
        int gz = min(zt * TZ + zr, RES - 1);
        int gy = min(yt * TY + yr, RES - 1);
        const float* src = vol + (size_t)(((gz << 8) + gy) << 8) + (lane << 2);
#if __has_builtin(__builtin_amdgcn_global_load_lds)
        __builtin_amdgcn_global_load_lds(
            (const __attribute__((address_space(1))) void*)src,
            (__attribute__((address_space(3))) void*)(dst + q * 256),
            16, 0, 0);
#else
        *(vfloat4*)(dst + q * 256 + (lane << 2)) = *(const vfloat4*)src;
#endif
    }
}

// ---- pass 2: persistent double-buffered LDS gather ----
// 256 blocks (1/CU), 8 tiles each. xcd=B&7, c=B>>3: zt=8*xcd+(c&7),
// yt = (c>>3)*8 + k, k=0..7. Stage tile k+1 while computing tile k.

__global__ __launch_bounds__(256) void VolumeExplicit_gather_kernel(
    const vfloat4* __restrict__ sorted,
    const unsigned* __restrict__ cursor,
    const float* __restrict__ vol,
    float* __restrict__ out)
{
    extern __shared__ float smem[];   // 2 * TILEF floats = 92160 B

    int t = threadIdx.x;
    int lane = t & 63;
    int w = t >> 6;                   // wave 0..3
    int B = blockIdx.x;
    int xcd = B & 7;
    int c = B >> 3;                   // 0..31
    int zt = (xcd << 3) | (c & 7);    // 0..63, pinned to this XCD's slab
    int ytBase = (c >> 3) << 3;       // 0,8,16,24

    stage_tile(vol, smem, zt, ytBase, lane, w);
    asm volatile("s_waitcnt vmcnt(0)");
    __syncthreads();

    #pragma unroll 1
    for (int k = 0; k < 8; ++k) {
        if (k < 7)
            stage_tile(vol, smem + ((k + 1) & 1) * TILEF, zt, ytBase + k + 1,
                       lane, w);

        int yt = ytBase + k;
        int bucket = zt * NYT + yt;
        unsigned count = cursor[bucket * CSTRIDE];
        if (count > CAP) count = CAP;
        const float* tile = smem + (k & 1) * TILEF;

        for (int s = t; s < (int)count; s += NTHREADS) {
            vfloat4 p = __builtin_nontemporal_load(&sorted[(size_t)bucket * CAP + s]);

            float ix = ((p.x * 2.0f + 1.0f) * (float)RES - 1.0f) * 0.5f;
            float iy = ((p.y * 2.0f + 1.0f) * (float)RES - 1.0f) * 0.5f;
            float iz = ((p.z * 2.0f + 1.0f) * (float)RES - 1.0f) * 0.5f;

            float x0f = floorf(ix), y0f = floorf(iy), z0f = floorf(iz);
            float tx = ix - x0f, ty = iy - y0f, tz = iz - z0f;

            int x0 = (int)x0f, y0 = (int)y0f, z0 = (int)z0f;
            int x1 = x0 + 1, y1 = y0 + 1, z1 = z0 + 1;

            float wx0 = (x0 >= 0 && x0 < RES) ? (1.0f - tx) : 0.0f;
            float wx1 = (x1 >= 0 && x1 < RES) ? tx : 0.0f;
            float wy0 = (y0 >= 0 && y0 < RES) ? (1.0f - ty) : 0.0f;
            float wy1 = (y1 >= 0 && y1 < RES) ? ty : 0.0f;
            float wz0 = (z0 >= 0 && z0 < RES) ? (1.0f - tz) : 0.0f;
            float wz1 = (z1 >= 0 && z1 < RES) ? tz : 0.0f;

            int xc0 = min(max(x0, 0), RES - 1), xc1 = min(max(x1, 0), RES - 1);
            int yc0 = min(max(y0, 0), RES - 1), yc1 = min(max(y1, 0), RES - 1);
            int zc0 = min(max(z0, 0), RES - 1), zc1 = min(max(z1, 0), RES - 1);

            // local tile coords (bucket key guarantees zc0 in [4zt,4zt+3],
            // yc0 in [8yt,8yt+7]; +1 neighbors stay inside the staged halo)
            int zl0 = zc0 - zt * TZ, zl1 = zc1 - zt * TZ;
            int yl0 = yc0 - yt * TY, yl1 = yc1 - yt * TY;

            int r00 = ((zl0 * 9 + yl0) << 8);
            int r01 = ((zl0 * 9 + yl1) << 8);
            int r10 = ((zl1 * 9 + yl0) << 8);
            int r11 = ((zl1 * 9 + yl1) << 8);

            float v000 = tile[r00 + xc0];
            float v001 = tile[r00 + xc1];
            float v010 = tile[r01 + xc0];
            float v011 = tile[r01 + xc1];
            float v100 = tile[r10 + xc0];
            float v101 = tile[r10 + xc1];
            float v110 = tile[r11 + xc0];
            float v111 = tile[r11 + xc1];

            float c00 = v000 * wx0 + v001 * wx1;
            float c01 = v010 * wx0 + v011 * wx1;
            float c10 = v100 * wx0 + v101 * wx1;
            float c11 = v110 * wx0 + v111 * wx1;
            float c0 = c00 * wy0 + c01 * wy1;
            float c1 = c10 * wy0 + c11 * wy1;
            float o = 100.0f * (c0 * wz0 + c1 * wz1);

            __builtin_nontemporal_store(o, &out[__float_as_uint(p.w)]);
        }

        // drain staging of tile k+1, then swap buffers
        asm volatile("s_waitcnt vmcnt(0)");
        __syncthreads();
    }
}

// ---- fallback: direct kernel (any shape / small workspace) ----

__global__ __launch_bounds__(256) void VolumeExplicit_29257317220866_kernel(
    const float* __restrict__ x,
    const float* __restrict__ vol,
    float* __restrict__ out,
    int n)
{
    int tid = blockIdx.x * blockDim.x + threadIdx.x;
    int half = n >> 1;
    if (tid >= half) return;
    int iA = tid;
    int iB = tid + half;

    float oA, oB;
    {
        float rx = __builtin_nontemporal_load(&x[3 * iA + 0]);
        float ry = __builtin_nontemporal_load(&x[3 * iA + 1]);
        float rz = __builtin_nontemporal_load(&x[3 * iA + 2]);
        oA = interp_point(vol, rx, ry, rz);
    }
    {
        float rx = __builtin_nontemporal_load(&x[3 * iB + 0]);
        float ry = __builtin_nontemporal_load(&x[3 * iB + 1]);
        float rz = __builtin_nontemporal_load(&x[3 * iB + 2]);
        oB = interp_point(vol, rx, ry, rz);
    }

    __builtin_nontemporal_store(oA, &out[iA]);
    __builtin_nontemporal_store(oB, &out[iB]);
}

extern "C" void kernel_launch(void* const* d_in, const int* in_sizes, int n_in,
                              void* d_out, int out_size, void* d_ws, size_t ws_size,
                              hipStream_t stream) {
    const float* x   = (const float*)d_in[0];   // [8, 65536, 3] fp32
    const float* vol = (const float*)d_in[1];   // [256,256,256] fp32
    float* out = (float*)d_out;                 // [8, 65536] fp32

    int n = out_size;                            // 524288 points
    size_t cursor_bytes = (size_t)NBKT * CSTRIDE * sizeof(unsigned); // 128 KB
    size_t need = cursor_bytes + (size_t)NBKT * CAP * sizeof(vfloat4); // ~11.6 MB

    if (n == 524288 && d_ws != nullptr && ws_size >= need) {
        unsigned* cursor = (unsigned*)d_ws;
        vfloat4* sorted  = (vfloat4*)((char*)d_ws + cursor_bytes);

        hipMemsetAsync(cursor, 0, cursor_bytes, stream);
        VolumeExplicit_scatter_kernel<<<n / 1024, 256, 0, stream>>>(
            x, vol, out, sorted, cursor);
        VolumeExplicit_gather_kernel<<<256, NTHREADS,
            2 * TILEF * sizeof(float), stream>>>(sorted, cursor, vol, out);
    } else {
        int half = n >> 1;
        int block = 256;
        int grid = (half + block - 1) / block;
        VolumeExplicit_29257317220866_kernel<<<grid, block, 0, stream>>>(x, vol, out, n);
    }
}

// Round 7
// 120.005 us; speedup vs baseline: 1.1276x; 1.1276x over previous
//
#include <hip/hip_runtime.h>

// Trilinear grid_sample (align_corners=False, zeros padding) of 256^3 fp32
// volume, scaled by 100.
//
// Round 9: revert to direct kernel; test the last untested lever (occupancy).
//   Rounds 3-8 falsified every sort/stage alternative: the scatter pass is
//   structurally >=13us and the staged gather >=25us -- sum never beats the
//   direct kernel's 42.9us. Direct kernel evidence: 129 MB cold random 64B
//   lines at 3.1 TB/s, time invariant to request count (8->4) -- but its
//   grid (1024 blocks, 2pt/thread) caps occupancy at 50%. This round:
//   1 pt/thread, 2048 blocks -> 100% grid occupancy, ~2x in-flight line
//   requests/CU. If MLP-limited -> ~30us; if service-rate-limited -> ~43us
//   and that is the roofline.

#define RES 256

// 2-wide float vector, alignment 4, so the compiler emits one
// global_load_dwordx2 for the (x0,x1) pair at any dword-aligned address.
typedef float f2a4 __attribute__((ext_vector_type(2), aligned(4)));

__global__ __launch_bounds__(256) void VolumeExplicit_29257317220866_kernel(
    const float* __restrict__ x,
    const float* __restrict__ vol,
    float* __restrict__ out,
    int n)
{
    int i = blockIdx.x * blockDim.x + threadIdx.x;
    if (i >= n) return;

    float gx = __builtin_nontemporal_load(&x[3 * i + 0]) * 2.0f;
    float gy = __builtin_nontemporal_load(&x[3 * i + 1]) * 2.0f;
    float gz = __builtin_nontemporal_load(&x[3 * i + 2]) * 2.0f;

    float ix = ((gx + 1.0f) * (float)RES - 1.0f) * 0.5f;
    float iy = ((gy + 1.0f) * (float)RES - 1.0f) * 0.5f;
    float iz = ((gz + 1.0f) * (float)RES - 1.0f) * 0.5f;

    float x0f = floorf(ix), y0f = floorf(iy), z0f = floorf(iz);
    float tx = ix - x0f, ty = iy - y0f, tz = iz - z0f;

    int x0 = (int)x0f, y0 = (int)y0f, z0 = (int)z0f;
    int x1 = x0 + 1, y1 = y0 + 1, z1 = z0 + 1;

    float wx0 = (x0 >= 0 && x0 < RES) ? (1.0f - tx) : 0.0f;
    float wx1 = (x1 >= 0 && x1 < RES) ? tx : 0.0f;
    float wy0 = (y0 >= 0 && y0 < RES) ? (1.0f - ty) : 0.0f;
    float wy1 = (y1 >= 0 && y1 < RES) ? ty : 0.0f;
    float wz0 = (z0 >= 0 && z0 < RES) ? (1.0f - tz) : 0.0f;
    float wz1 = (z1 >= 0 && z1 < RES) ? tz : 0.0f;

    // (x0,x1) pair -> one dwordx2 at xb=clamp(x0,0,254); weight mapping
    // swaps when x0 is clamped (x0=-1 or 255); fully-out cases have both
    // weights 0 (verified round 5, absmax 3.8e-6).
    int xb = min(max(x0, 0), RES - 2);
    bool e0 = (x0 == xb);
    float wxa = e0 ? wx0 : wx1;   // weight applied to f.x
    float wxb = e0 ? wx1 : wx0;   // weight applied to f.y

    int yc0 = min(max(y0, 0), RES - 1), yc1 = min(max(y1, 0), RES - 1);
    int zc0 = min(max(z0, 0), RES - 1), zc1 = min(max(z1, 0), RES - 1);

    int r00 = (zc0 * RES + yc0) * RES;
    int r01 = (zc0 * RES + yc1) * RES;
    int r10 = (zc1 * RES + yc0) * RES;
    int r11 = (zc1 * RES + yc1) * RES;

    // all 4 dwordx2 taps issued back-to-back, in flight together
    f2a4 f00 = *reinterpret_cast<const f2a4*>(vol + r00 + xb);
    f2a4 f01 = *reinterpret_cast<const f2a4*>(vol + r01 + xb);
    f2a4 f10 = *reinterpret_cast<const f2a4*>(vol + r10 + xb);
    f2a4 f11 = *reinterpret_cast<const f2a4*>(vol + r11 + xb);

    float c00 = f00.x * wxa + f00.y * wxb;
    float c01 = f01.x * wxa + f01.y * wxb;
    float c10 = f10.x * wxa + f10.y * wxb;
    float c11 = f11.x * wxa + f11.y * wxb;
    float c0 = c00 * wy0 + c01 * wy1;
    float c1 = c10 * wy0 + c11 * wy1;
    float o = 100.0f * (c0 * wz0 + c1 * wz1);

    __builtin_nontemporal_store(o, &out[i]);
}

extern "C" void kernel_launch(void* const* d_in, const int* in_sizes, int n_in,
                              void* d_out, int out_size, void* d_ws, size_t ws_size,
                              hipStream_t stream) {
    const float* x   = (const float*)d_in[0];   // [8, 65536, 3] fp32
    const float* vol = (const float*)d_in[1];   // [256,256,256] fp32
    float* out = (float*)d_out;                 // [8, 65536] fp32

    int n = out_size;          // 524288 points
    int block = 256;
    int grid = (n + block - 1) / block;   // 2048 blocks -> 8192 waves (100% occ)
    VolumeExplicit_29257317220866_kernel<<<grid, block, 0, stream>>>(x, vol, out, n);
}